// Round 12
// baseline (84.505 us; speedup 1.0000x reference)
//
#include <hip/hip_runtime.h>
#include <math.h>

typedef _Float16 f16;
typedef _Float16 f16x8 __attribute__((ext_vector_type(8)));
typedef float f32x4 __attribute__((ext_vector_type(4)));

// workspace: [0,16384) staged f16 weights; [16384, +B*16) qin
#define WS_QIN_OFF 16384
#define OW1   0      // [16][32] conv1 [oc][k] k=gk*8+ii: gk=ky, ii=1..3 -> kx=ii-1
#define OW2   512    // [16][96] conv2 [oc][pos12][ic8], pos>=9 zero
#define OW3   2048   // [16][160] conv3 [oc][k], k=pos*16+ic, pos>=9 zero
#define OPOOL 4608   // [16][64] 36x pool matrix (entries 9/6/4 exact f16)

// 4-byte-aligned 8-byte LDS load type -> compiler emits ds_read2_b32 (one
// instruction) instead of asserting 8B alignment (misaligned b64 hazard).
struct __attribute__((aligned(4))) u32pair { unsigned a, b; };

// wave-internal fence: drain this wave's LDS/VMEM so cross-lane RAW is safe
// without a block barrier (each wave owns its LDS region).
__device__ __forceinline__ void wfence(){
  __builtin_amdgcn_sched_barrier(0);
  asm volatile("s_waitcnt vmcnt(0) lgkmcnt(0)" ::: "memory");
  __builtin_amdgcn_sched_barrier(0);
}

// ---------------------------------------------------------------------------
__global__ void precompute_weights(const float* __restrict__ w1g,
                                   const float* __restrict__ w2g,
                                   const float* __restrict__ w3g,
                                   f16* __restrict__ wsw){
  const int tid = threadIdx.x;
  // conv1 weights (R4-proven): rows oc<8, chunk gk=ky, ii=0 is the kx=-1
  // garbage slot (zero weight), ii=1..3 -> kx=ii-1, ii>=4 zero.
  for (int i=tid; i<512; i+=256){
    int oc = i >> 5, k = i & 31, gk = k >> 3, ii = k & 7;
    float v = 0.f;
    if (oc < 8 && gk < 3 && ii >= 1 && ii <= 3) v = w1g[oc*9 + gk*3 + (ii-1)];
    wsw[OW1 + i] = (f16)v;
  }
  for (int i=tid; i<1536; i+=256){
    int oc = i/96, r = i%96, p = r>>3, ic = r&7;
    wsw[OW2 + i] = (f16)(p < 9 ? w2g[oc*72 + ic*9 + p] : 0.f);
  }
  for (int i=tid; i<2560; i+=256){
    int oc = i/160, k = i%160, pos = k>>4, ic = k&15;
    wsw[OW3 + i] = (f16)(pos < 9 ? w3g[oc*144 + ic*9 + pos] : 0.f);
  }
  // 36x adaptive-pool matrix: P36[pq][pix], exact {9,6,4} in f16
  for (int i=tid; i<1024; i+=256){
    int pq = i >> 6, pix = i & 63;
    float v = 0.f;
    if (pix < 49){
      int p = pq >> 2, q = pq & 3, ii = pix/7, jj = pix%7;
      int sp = (p*7) >> 2, ep = (7*(p+1)+3) >> 2;
      int sq = (q*7) >> 2, eq = (7*(q+1)+3) >> 2;
      if (ii >= sp && ii < ep && jj >= sq && jj < eq)
        v = 36.f / (float)((ep-sp)*(eq-sq));
    }
    wsw[OPOOL + i] = (f16)v;
  }
}

// ---------------------------------------------------------------------------
// One WAVE per sample, 4 waves/block, zero block barriers. All MFMA operands
// indexed with kappa(g,i)=g*8+i on both operands (HW k-perm cancels;
// validated R2-R7). D-mapping (pinned R2 conv2 + R4 conv3): D rows <- arg0's
// per-lane index, D cols <- arg1's; lane (l15,g) reg j holds D[g*4+j][l15].
// Garbage-tolerance rules for border-only zeroing:
//   A[m][k] garbage (even NaN) -> only D row m;  B[k][n] garbage -> only
//   D col n;  k-slots with NONZERO weight must be real/zero-pad; k-slots
//   with zero weight need only FINITE data.
// R8 bug fixed here: with 17 c1s cols, col 15 is read by tap kx=2 at valid
// output x=13 with NONZERO weight -> must be zeroed (R8 zeroed only 0,16).
// ---------------------------------------------------------------------------
__global__ __launch_bounds__(256, 4) void classical_kernel(
    const float* __restrict__ xg,
    const float* __restrict__ b1g, const float* __restrict__ b2g,
    const float* __restrict__ b3g,
    const float* __restrict__ fcwg, const float* __restrict__ fcbg,
    const f16* __restrict__ wsw, float* __restrict__ qin, int B)
{
  // per-wave 8240B: region A [0,3888)    = xs [30][36] f16, later c2ps [81][24]
  //                 region B [3888,8240) = c1s [16][17][8] f16 (4352B, odd unit
  //                 stride 272B -> uniform conv2 bank spread), later c3t [16][72]
  __shared__ __align__(16) unsigned char pw[4][8240];

  const int tid = threadIdx.x, lane = tid & 63, wv = tid >> 6;
  const int l15 = lane & 15, g = lane >> 4;

  const int b = blockIdx.x*4 + wv;
  if (b >= B) return;

  f16* xs   = (f16*)&pw[wv][0];       // [30][36], col = x_img+4, row = y_img+1
  f16* c2ps = xs;                     // overlay: [81 pos][24 ch]
  f16* c1s  = (f16*)&pw[wv][3888];    // [16 row][17 col][8 ic] = 4352B
  f16* c3t  = c1s;                    // overlay: [16 oc][72 pix] (144B rows)

  // ---- border-only zero: xs rows 0,29 + cols 2,3 (rows 1..28) = 64 u32 ----
  {
    unsigned* pz = (unsigned*)xs;     // rows of 18 dw
    int dw;
    if (lane < 18)      dw = lane;                      // row 0
    else if (lane < 36) dw = 29*18 + (lane - 18);       // row 29
    else                dw = (lane - 35)*18 + 1;        // rows 1..28, f16 cols 2,3
    pz[dw] = 0u;
  }
  // ---- border-only zero: c1s rows 0,15 + cols 0,15,16 (76 b128 units) ----
  {
    const f32x4 z4 = {0.f,0.f,0.f,0.f};
    f32x4* pz = (f32x4*)c1s;          // b128 unit idx = row*17 + col
    for (int i=lane; i<76; i+=64){
      int dst;
      if (i < 17)      dst = i;                      // row 0
      else if (i < 34) dst = 255 + (i - 17);         // row 15 (15*17=255)
      else if (i < 48) dst = (i - 33)*17;            // col 0,  rows 1..14
      else if (i < 62) dst = (i - 47)*17 + 15;       // col 15, rows 1..14
      else             dst = (i - 61)*17 + 16;       // col 16, rows 1..14
      pz[dst] = z4;
    }
  }

  // ---- stage input: float4 global -> 4xf16 b64 LDS ----
  {
    const float4* xg4 = (const float4*)(xg + (size_t)b*784);
    #pragma unroll
    for (int r=0; r<4; ++r){
      const int idx = r*64 + lane;
      if (idx < 196){
        float4 v = xg4[idx];
        int y = idx/7, xq = idx - y*7;
        union { f16 h[4]; unsigned long long u; } pk;
        pk.h[0]=(f16)v.x; pk.h[1]=(f16)v.y; pk.h[2]=(f16)v.z; pk.h[3]=(f16)v.w;
        *(unsigned long long*)&xs[(y+1)*36 + xq*4 + 4] = pk.u;
      }
    }
  }
  wfence();

  // ---- conv1 (1->8, stride2, pad1) + relu via MFMA (R4-proven form) ----
  // A=weights (rows oc), B=image: chunk g = ky (g=3 all-zero weights), taps
  // i=0 -> kx=-1 (zero wt), i=1..3 -> kx=i-1, i>=4 zeroed in-reg.
  // D[oc=g*4+j][x=l15], write b64 (4 ic). Image read = ONE 8B load (read2).
  {
    const f16x8 aw = *(const f16x8*)&wsw[OW1 + l15*32 + g*8];
    const float4 bv = ((const float4*)b1g)[g & 1];   // oc g*4..g*4+3 (g<2)
    const unsigned* xsw = (const unsigned*)xs;       // u32 rows of 18
    for (int oy=0; oy<14; ++oy){
      const int bu = (2*oy + g)*18 + l15 + 1;        // f16 col 2*l15+2
      const u32pair rr = *(const u32pair*)&xsw[bu];
      union { unsigned u[4]; f16x8 v; } bf;
      bf.u[0] = rr.a; bf.u[1] = rr.b;
      bf.u[2] = 0u;   bf.u[3] = 0u;
      f32x4 acc = {0.f,0.f,0.f,0.f};
      acc = __builtin_amdgcn_mfma_f32_16x16x32_f16(aw, bf.v, acc, 0,0,0);
      if (g < 2 && l15 < 14){
        union { f16 h[4]; unsigned long long u; } pk;
        #pragma unroll
        for (int j=0;j<4;++j) pk.h[j] = (f16)fmaxf(acc[j] + bv[j], 0.f);
        *(unsigned long long*)&c1s[((oy+1)*17 + (l15+1))*8 + g*4] = pk.u;
      }
    }
  }
  wfence();

  // ---- conv2 (8->16, pad1) + maxpool2 + bias + relu via MFMA ----
  // A=image (m=x), B=weights (n=oc); pool folds in-register.
  // Reads at valid rows m<=13 touch cols 0..15 (all written or zeroed);
  // cols 16/17 only feed discarded D rows m=14,15 (finite garbage OK).
  {
    const f16x8 bf0 = *(const f16x8*)&wsw[OW2 + l15*96      + g*8];
    const f16x8 bf1 = *(const f16x8*)&wsw[OW2 + l15*96 + 32 + g*8];
    const f16x8 bf2 = *(const f16x8*)&wsw[OW2 + l15*96 + 64 + g*8];
    const float bias2 = b2g[l15];
    // border-only zero of c2ps (overlays dead xs): 32 border positions of the
    // 9x9 grid x ic0..15 (the only channels conv3 reads) = 64 b128, 1/lane.
    {
      const f32x4 z4 = {0.f,0.f,0.f,0.f};
      const int i = lane >> 1;
      int p;
      if (i < 9)       p = i;                 // row 0
      else if (i < 18) p = i + 63;            // row 8: 72..80
      else if (i < 25) p = 9*(i - 17);        // col 0: 9,18,..,63
      else             p = 9*(i - 24) + 8;    // col 8: 17,26,..,71
      *(f32x4*)&c2ps[p*24 + (lane & 1)*8] = z4;
    }
    const int p0 = g,     r0o = p0/3, c0o = p0%3;
    const int p1 = 4 + g, r1o = p1/3, c1o = p1%3;
    float hA = 0.f, hB = 0.f;
    for (int y=0; y<14; ++y){
      f16x8 a0 = *(const f16x8*)&c1s[((y + r0o)*17 + l15 + c0o)*8];
      f16x8 a1 = *(const f16x8*)&c1s[((y + r1o)*17 + l15 + c1o)*8];
      f16x8 a2 = *(const f16x8*)&c1s[((y + 2  )*17 + l15 + 2  )*8];
      f32x4 acc = {0.f,0.f,0.f,0.f};
      acc = __builtin_amdgcn_mfma_f32_16x16x32_f16(a0, bf0, acc, 0,0,0);
      acc = __builtin_amdgcn_mfma_f32_16x16x32_f16(a1, bf1, acc, 0,0,0);
      acc = __builtin_amdgcn_mfma_f32_16x16x32_f16(a2, bf2, acc, 0,0,0);
      const float m0 = fmaxf(acc[0], acc[1]);   // x = 4g,4g+1   -> px=2g
      const float m1 = fmaxf(acc[2], acc[3]);   // x = 4g+2,4g+3 -> px=2g+1
      if ((y & 1) == 0){ hA = m0; hB = m1; }
      else {
        const int py = y >> 1;
        const float vA = fmaxf(fmaxf(hA, m0) + bias2, 0.f);
        const float vB = fmaxf(fmaxf(hB, m1) + bias2, 0.f);
        c2ps[((py+1)*9 + (2*g+1))*24 + l15] = (f16)vA;        // px=2g
        if (g < 3)
          c2ps[((py+1)*9 + (2*g+2))*24 + l15] = (f16)vB;      // px=2g+1
      }
    }
  }
  wfence();

  // ---- conv3 (16->16, pad1) + bias + relu : A=image, B=weights ----
  // D[m=pix-in-tile=g*4+j][n=oc=l15]; store c3t[oc=l15][pix], b64.
  // Tile3 pix 49..63 are clamped duplicates of pix 48 (finite), zero pool wt.
  {
    f16x8 cf[5];
    #pragma unroll
    for (int kk=0; kk<5; ++kk)
      cf[kk] = *(const f16x8*)&wsw[OW3 + l15*160 + kk*32 + g*8];
    const float bias3 = b3g[l15];
    const int gh = g >> 1, icb = (g & 1)*8;
    #pragma unroll
    for (int tile=0; tile<4; ++tile){
      unsigned m = (unsigned)(tile*16 + l15); if (m > 48u) m = 48u;
      const int rcb = (int)(m/7u)*9 + (int)(m%7u);
      f32x4 acc = {0.f,0.f,0.f,0.f};
      #pragma unroll
      for (int kk=0; kk<5; ++kk){
        int p = 2*kk + gh; if (p > 8) p = 8;      // weight rows pos>=9 zero
        f16x8 a = *(const f16x8*)&c2ps[(rcb + (p/3)*9 + (p%3))*24 + icb];
        acc = __builtin_amdgcn_mfma_f32_16x16x32_f16(a, cf[kk], acc, 0,0,0);
      }
      union { f16 h[4]; unsigned long long u; } pk;
      #pragma unroll
      for (int j=0;j<4;++j) pk.h[j] = (f16)fmaxf(acc[j] + bias3, 0.f);
      *(unsigned long long*)&c3t[l15*72 + tile*16 + g*4] = pk.u;
    }
  }
  wfence();

  // ---- adaptive pool as 2 MFMAs: D[m=pq][n=oc] = 36*feat[oc][pq] ----
  // A=P36 (arg0, rows pq), B=c3t (arg1, cols oc). Lane reg j holds
  // 36*feat[oc=l15][pq=g*4+j] -> flatten t = l15*16 + g*4 + j.
  f32x4 pacc = {0.f,0.f,0.f,0.f};
  {
    const f16x8 pA0 = *(const f16x8*)&wsw[OPOOL + l15*64      + g*8];
    const f16x8 pA1 = *(const f16x8*)&wsw[OPOOL + l15*64 + 32 + g*8];
    const f16x8 pB0 = *(const f16x8*)&c3t[l15*72      + g*8];
    const f16x8 pB1 = *(const f16x8*)&c3t[l15*72 + 32 + g*8];
    pacc = __builtin_amdgcn_mfma_f32_16x16x32_f16(pA0, pB0, pacc, 0,0,0);
    pacc = __builtin_amdgcn_mfma_f32_16x16x32_f16(pA1, pB1, pacc, 0,0,0);
  }

  // ---- fc (256->4) + tanh*pi : shfl_xor butterfly (R3/R6-proven) ----
  {
    const float4 fw0 = *(const float4*)&fcwg[      l15*16 + g*4];
    const float4 fw1 = *(const float4*)&fcwg[256 + l15*16 + g*4];
    const float4 fw2 = *(const float4*)&fcwg[512 + l15*16 + g*4];
    const float4 fw3 = *(const float4*)&fcwg[768 + l15*16 + g*4];
    float s0 = pacc[0]*fw0.x + pacc[1]*fw0.y + pacc[2]*fw0.z + pacc[3]*fw0.w;
    float s1 = pacc[0]*fw1.x + pacc[1]*fw1.y + pacc[2]*fw1.z + pacc[3]*fw1.w;
    float s2 = pacc[0]*fw2.x + pacc[1]*fw2.y + pacc[2]*fw2.z + pacc[3]*fw2.w;
    float s3 = pacc[0]*fw3.x + pacc[1]*fw3.y + pacc[2]*fw3.z + pacc[3]*fw3.w;
    #pragma unroll
    for (int off=32; off; off>>=1){
      s0 += __shfl_xor(s0, off); s1 += __shfl_xor(s1, off);
      s2 += __shfl_xor(s2, off); s3 += __shfl_xor(s3, off);
    }
    if (lane < 4){
      const float s = (lane==0)?s0:(lane==1)?s1:(lane==2)?s2:s3;
      qin[(size_t)b*4 + lane] =
          tanhf(s*(1.f/36.f) + fcbg[lane]) * 3.14159265358979323846f;
    }
  }
}

// ---------------------------------------------------------------------------
// Kernel B: per-thread 4-qubit statevector sim + classifier head.
// wire w <-> bit mask (8 >> w)
// ---------------------------------------------------------------------------
template<int M>
__device__ __forceinline__ void g_ry(float* re, float* im, float c, float s){
  #pragma unroll
  for (int i=0;i<16;++i){
    if ((i & M)==0){
      const int j = i | M;
      const float r0=re[i], r1=re[j], q0=im[i], q1=im[j];
      re[i]=c*r0 - s*r1; re[j]=s*r0 + c*r1;
      im[i]=c*q0 - s*q1; im[j]=s*q0 + c*q1;
    }
  }
}
template<int M>
__device__ __forceinline__ void g_rz(float* re, float* im, float c, float s){
  #pragma unroll
  for (int i=0;i<16;++i){
    const float r=re[i], q=im[i];
    if ((i & M)==0){ re[i]=c*r + s*q; im[i]=c*q - s*r; }
    else           { re[i]=c*r - s*q; im[i]=c*q + s*r; }
  }
}
template<int CM,int TM>
__device__ __forceinline__ void g_cnot(float* re, float* im){
  #pragma unroll
  for (int i=0;i<16;++i){
    if ((i & CM) && !(i & TM)){
      const int j = i | TM;
      float t=re[i]; re[i]=re[j]; re[j]=t;
      t=im[i]; im[i]=im[j]; im[j]=t;
    }
  }
}

__global__ __launch_bounds__(256) void quantum_kernel(
    const float* __restrict__ qin, const float* __restrict__ qwg,
    const float* __restrict__ c1wg, const float* __restrict__ c1bg,
    const float* __restrict__ c2wg, const float* __restrict__ c2bg,
    float* __restrict__ out, int B)
{
  __shared__ float qc[32], qs[32], w1s[128], b1s[32], w2s[320], b2s[16];
  const int tid = threadIdx.x;
  if (tid < 32){ const float a = qwg[tid]*0.5f; qc[tid]=cosf(a); qs[tid]=sinf(a); }
  if (tid < 128) w1s[tid] = c1wg[tid];
  if (tid < 32)  b1s[tid] = c1bg[tid];
  for (int i=tid; i<320; i+=256) w2s[i] = c2wg[i];
  if (tid < 10)  b2s[tid] = c2bg[tid];
  __syncthreads();

  const int b = blockIdx.x*256 + tid;
  if (b >= B) return;

  const float4 ang = *(const float4*)(qin + (size_t)b*4);

  float re[16], im[16];
  #pragma unroll
  for (int i=0;i<16;++i){ re[i]=0.f; im[i]=0.f; }
  re[0] = 1.f;

  {
    float c,s;
    sincosf(ang.x*0.5f, &s, &c); g_ry<8>(re,im,c,s);
    sincosf(ang.y*0.5f, &s, &c); g_ry<4>(re,im,c,s);
    sincosf(ang.z*0.5f, &s, &c); g_ry<2>(re,im,c,s);
    sincosf(ang.w*0.5f, &s, &c); g_ry<1>(re,im,c,s);
  }

  #pragma unroll
  for (int l=0; l<4; ++l){
    const int o = l*8;
    g_ry<8>(re,im,qc[o+0],qs[o+0]);  g_rz<8>(re,im,qc[o+1],qs[o+1]);
    g_ry<4>(re,im,qc[o+2],qs[o+2]);  g_rz<4>(re,im,qc[o+3],qs[o+3]);
    g_ry<2>(re,im,qc[o+4],qs[o+4]);  g_rz<2>(re,im,qc[o+5],qs[o+5]);
    g_ry<1>(re,im,qc[o+6],qs[o+6]);  g_rz<1>(re,im,qc[o+7],qs[o+7]);
    g_cnot<8,4>(re,im); g_cnot<4,2>(re,im); g_cnot<2,1>(re,im); g_cnot<1,8>(re,im);
  }

  float p[16];
  #pragma unroll
  for (int i=0;i<16;++i) p[i] = re[i]*re[i] + im[i]*im[i];
  float z0=0.f, z1=0.f, z2=0.f, z3=0.f;
  #pragma unroll
  for (int i=0;i<16;++i){
    z0 += (i & 8) ? -p[i] : p[i];
    z1 += (i & 4) ? -p[i] : p[i];
    z2 += (i & 2) ? -p[i] : p[i];
    z3 += (i & 1) ? -p[i] : p[i];
  }

  float h[32];
  #pragma unroll
  for (int o=0;o<32;++o){
    const float v = b1s[o] + z0*w1s[o*4+0] + z1*w1s[o*4+1]
                           + z2*w1s[o*4+2] + z3*w1s[o*4+3];
    h[o] = fmaxf(v, 0.f);
  }
  #pragma unroll
  for (int o=0;o<10;++o){
    float v = b2s[o];
    #pragma unroll
    for (int k=0;k<32;++k) v += h[k]*w2s[o*32+k];
    out[(size_t)b*10 + o] = v;
  }
}

// ---------------------------------------------------------------------------
extern "C" void kernel_launch(void* const* d_in, const int* in_sizes, int n_in,
                              void* d_out, int out_size, void* d_ws, size_t ws_size,
                              hipStream_t stream)
{
  const float* x   = (const float*)d_in[0];
  const float* w1  = (const float*)d_in[1];
  const float* b1  = (const float*)d_in[2];
  const float* w2  = (const float*)d_in[3];
  const float* b2  = (const float*)d_in[4];
  const float* w3  = (const float*)d_in[5];
  const float* b3  = (const float*)d_in[6];
  const float* fcw = (const float*)d_in[7];
  const float* fcb = (const float*)d_in[8];
  const float* qw  = (const float*)d_in[9];
  const float* c1w = (const float*)d_in[10];
  const float* c1b = (const float*)d_in[11];
  const float* c2w = (const float*)d_in[12];
  const float* c2b = (const float*)d_in[13];
  float* outp = (float*)d_out;

  const int B = in_sizes[0] / 784;
  f16*   wsw = (f16*)d_ws;
  float* qin = (float*)((char*)d_ws + WS_QIN_OFF);

  precompute_weights<<<1, 256, 0, stream>>>(w1, w2, w3, wsw);

  classical_kernel<<<(B+3)/4, 256, 0, stream>>>(x, b1, b2, b3, fcw, fcb,
                                                wsw, qin, B);

  quantum_kernel<<<(B+255)/256, 256, 0, stream>>>(qin, qw, c1w, c1b,
                                                  c2w, c2b, outp, B);
}

// Round 13
// 84.438 us; speedup vs baseline: 1.0008x; 1.0008x over previous
//
#include <hip/hip_runtime.h>
#include <math.h>

typedef _Float16 f16;
typedef _Float16 f16x8 __attribute__((ext_vector_type(8)));
typedef float f32x4 __attribute__((ext_vector_type(4)));

// workspace: [0,16384) staged f16 weights; [16384, +B*16) qin
#define WS_QIN_OFF 16384
#define OW1   0      // [16][32] conv1 [oc][k] k=gk*8+ii: gk=ky, ii=1..3 -> kx=ii-1
#define OW2   512    // [16][96] conv2 [oc][pos12][ic8], pos>=9 zero
#define OW3   2048   // [16][160] conv3 [oc][k], k=pos*16+ic, pos>=9 zero
#define OPOOL 4608   // [16][64] 36x pool matrix (entries 9/6/4 exact f16)

// 4-byte-aligned 8-byte LDS load type -> compiler emits ds_read2_b32 (one
// instruction) instead of asserting 8B alignment (misaligned b64 hazard).
struct __attribute__((aligned(4))) u32pair { unsigned a, b; };

// wave-internal fence: drain this wave's LDS/VMEM so cross-lane RAW is safe
// without a block barrier (each wave owns its LDS region).
__device__ __forceinline__ void wfence(){
  __builtin_amdgcn_sched_barrier(0);
  asm volatile("s_waitcnt vmcnt(0) lgkmcnt(0)" ::: "memory");
  __builtin_amdgcn_sched_barrier(0);
}

// ---------------------------------------------------------------------------
__global__ void precompute_weights(const float* __restrict__ w1g,
                                   const float* __restrict__ w2g,
                                   const float* __restrict__ w3g,
                                   f16* __restrict__ wsw){
  const int tid = threadIdx.x;
  // conv1 weights (R4-proven): rows oc<8, chunk gk=ky, ii=0 is the kx=-1
  // garbage slot (zero weight), ii=1..3 -> kx=ii-1, ii>=4 zero.
  for (int i=tid; i<512; i+=256){
    int oc = i >> 5, k = i & 31, gk = k >> 3, ii = k & 7;
    float v = 0.f;
    if (oc < 8 && gk < 3 && ii >= 1 && ii <= 3) v = w1g[oc*9 + gk*3 + (ii-1)];
    wsw[OW1 + i] = (f16)v;
  }
  for (int i=tid; i<1536; i+=256){
    int oc = i/96, r = i%96, p = r>>3, ic = r&7;
    wsw[OW2 + i] = (f16)(p < 9 ? w2g[oc*72 + ic*9 + p] : 0.f);
  }
  for (int i=tid; i<2560; i+=256){
    int oc = i/160, k = i%160, pos = k>>4, ic = k&15;
    wsw[OW3 + i] = (f16)(pos < 9 ? w3g[oc*144 + ic*9 + pos] : 0.f);
  }
  // 36x adaptive-pool matrix: P36[pq][pix], exact {9,6,4} in f16
  for (int i=tid; i<1024; i+=256){
    int pq = i >> 6, pix = i & 63;
    float v = 0.f;
    if (pix < 49){
      int p = pq >> 2, q = pq & 3, ii = pix/7, jj = pix%7;
      int sp = (p*7) >> 2, ep = (7*(p+1)+3) >> 2;
      int sq = (q*7) >> 2, eq = (7*(q+1)+3) >> 2;
      if (ii >= sp && ii < ep && jj >= sq && jj < eq)
        v = 36.f / (float)((ep-sp)*(eq-sq));
    }
    wsw[OPOOL + i] = (f16)v;
  }
}

// ---------------------------------------------------------------------------
// One WAVE per sample, 4 waves/block, zero block barriers. All MFMA operands
// indexed with kappa(g,i)=g*8+i on both operands (HW k-perm cancels;
// validated R2-R7). D-mapping (pinned R2 conv2 + R4 conv3): D rows <- arg0's
// per-lane index, D cols <- arg1's; lane (l15,g) reg j holds D[g*4+j][l15].
// Garbage-tolerance rules for border-only zeroing:
//   A[m][k] garbage (even NaN) -> only D row m;  B[k][n] garbage -> only
//   D col n;  k-slots with NONZERO weight must be real/zero-pad; k-slots
//   with zero weight need only FINITE data.
// R8 bug fixed here: with 17 c1s cols, col 15 is read by tap kx=2 at valid
// output x=13 with NONZERO weight -> must be zeroed (R8 zeroed only 0,16).
// ---------------------------------------------------------------------------
__global__ __launch_bounds__(256, 4) void classical_kernel(
    const float* __restrict__ xg,
    const float* __restrict__ b1g, const float* __restrict__ b2g,
    const float* __restrict__ b3g,
    const float* __restrict__ fcwg, const float* __restrict__ fcbg,
    const f16* __restrict__ wsw, float* __restrict__ qin, int B)
{
  // per-wave 8240B: region A [0,3888)    = xs [30][36] f16, later c2ps [81][24]
  //                 region B [3888,8240) = c1s [16][17][8] f16 (4352B, odd unit
  //                 stride 272B -> uniform conv2 bank spread), later c3t [16][72]
  __shared__ __align__(16) unsigned char pw[4][8240];

  const int tid = threadIdx.x, lane = tid & 63, wv = tid >> 6;
  const int l15 = lane & 15, g = lane >> 4;

  const int b = blockIdx.x*4 + wv;
  if (b >= B) return;

  f16* xs   = (f16*)&pw[wv][0];       // [30][36], col = x_img+4, row = y_img+1
  f16* c2ps = xs;                     // overlay: [81 pos][24 ch]
  f16* c1s  = (f16*)&pw[wv][3888];    // [16 row][17 col][8 ic] = 4352B
  f16* c3t  = c1s;                    // overlay: [16 oc][72 pix] (144B rows)

  // ---- border-only zero: xs rows 0,29 + cols 2,3 (rows 1..28) = 64 u32 ----
  {
    unsigned* pz = (unsigned*)xs;     // rows of 18 dw
    int dw;
    if (lane < 18)      dw = lane;                      // row 0
    else if (lane < 36) dw = 29*18 + (lane - 18);       // row 29
    else                dw = (lane - 35)*18 + 1;        // rows 1..28, f16 cols 2,3
    pz[dw] = 0u;
  }
  // ---- border-only zero: c1s rows 0,15 + cols 0,15,16 (76 b128 units) ----
  {
    const f32x4 z4 = {0.f,0.f,0.f,0.f};
    f32x4* pz = (f32x4*)c1s;          // b128 unit idx = row*17 + col
    for (int i=lane; i<76; i+=64){
      int dst;
      if (i < 17)      dst = i;                      // row 0
      else if (i < 34) dst = 255 + (i - 17);         // row 15 (15*17=255)
      else if (i < 48) dst = (i - 33)*17;            // col 0,  rows 1..14
      else if (i < 62) dst = (i - 47)*17 + 15;       // col 15, rows 1..14
      else             dst = (i - 61)*17 + 16;       // col 16, rows 1..14
      pz[dst] = z4;
    }
  }

  // ---- stage input: float4 global -> 4xf16 b64 LDS ----
  {
    const float4* xg4 = (const float4*)(xg + (size_t)b*784);
    #pragma unroll
    for (int r=0; r<4; ++r){
      const int idx = r*64 + lane;
      if (idx < 196){
        float4 v = xg4[idx];
        int y = idx/7, xq = idx - y*7;
        union { f16 h[4]; unsigned long long u; } pk;
        pk.h[0]=(f16)v.x; pk.h[1]=(f16)v.y; pk.h[2]=(f16)v.z; pk.h[3]=(f16)v.w;
        *(unsigned long long*)&xs[(y+1)*36 + xq*4 + 4] = pk.u;
      }
    }
  }
  wfence();

  // ---- conv1 (1->8, stride2, pad1) + relu via MFMA (R4-proven form) ----
  // A=weights (rows oc), B=image: chunk g = ky (g=3 all-zero weights), taps
  // i=0 -> kx=-1 (zero wt), i=1..3 -> kx=i-1, i>=4 zeroed in-reg.
  // D[oc=g*4+j][x=l15], write b64 (4 ic). Image read = ONE 8B load (read2).
  {
    const f16x8 aw = *(const f16x8*)&wsw[OW1 + l15*32 + g*8];
    const float4 bv = ((const float4*)b1g)[g & 1];   // oc g*4..g*4+3 (g<2)
    const unsigned* xsw = (const unsigned*)xs;       // u32 rows of 18
    for (int oy=0; oy<14; ++oy){
      const int bu = (2*oy + g)*18 + l15 + 1;        // f16 col 2*l15+2
      const u32pair rr = *(const u32pair*)&xsw[bu];
      union { unsigned u[4]; f16x8 v; } bf;
      bf.u[0] = rr.a; bf.u[1] = rr.b;
      bf.u[2] = 0u;   bf.u[3] = 0u;
      f32x4 acc = {0.f,0.f,0.f,0.f};
      acc = __builtin_amdgcn_mfma_f32_16x16x32_f16(aw, bf.v, acc, 0,0,0);
      if (g < 2 && l15 < 14){
        union { f16 h[4]; unsigned long long u; } pk;
        #pragma unroll
        for (int j=0;j<4;++j) pk.h[j] = (f16)fmaxf(acc[j] + bv[j], 0.f);
        *(unsigned long long*)&c1s[((oy+1)*17 + (l15+1))*8 + g*4] = pk.u;
      }
    }
  }
  wfence();

  // ---- conv2 (8->16, pad1) + maxpool2 + bias + relu via MFMA ----
  // A=image (m=x), B=weights (n=oc); pool folds in-register.
  // Reads at valid rows m<=13 touch cols 0..15 (all written or zeroed);
  // cols 16/17 only feed discarded D rows m=14,15 (finite garbage OK).
  {
    const f16x8 bf0 = *(const f16x8*)&wsw[OW2 + l15*96      + g*8];
    const f16x8 bf1 = *(const f16x8*)&wsw[OW2 + l15*96 + 32 + g*8];
    const f16x8 bf2 = *(const f16x8*)&wsw[OW2 + l15*96 + 64 + g*8];
    const float bias2 = b2g[l15];
    // border-only zero of c2ps (overlays dead xs): 32 border positions of the
    // 9x9 grid x ic0..15 (the only channels conv3 reads) = 64 b128, 1/lane.
    {
      const f32x4 z4 = {0.f,0.f,0.f,0.f};
      const int i = lane >> 1;
      int p;
      if (i < 9)       p = i;                 // row 0
      else if (i < 18) p = i + 63;            // row 8: 72..80
      else if (i < 25) p = 9*(i - 17);        // col 0: 9,18,..,63
      else             p = 9*(i - 24) + 8;    // col 8: 17,26,..,71
      *(f32x4*)&c2ps[p*24 + (lane & 1)*8] = z4;
    }
    const int p0 = g,     r0o = p0/3, c0o = p0%3;
    const int p1 = 4 + g, r1o = p1/3, c1o = p1%3;
    float hA = 0.f, hB = 0.f;
    for (int y=0; y<14; ++y){
      f16x8 a0 = *(const f16x8*)&c1s[((y + r0o)*17 + l15 + c0o)*8];
      f16x8 a1 = *(const f16x8*)&c1s[((y + r1o)*17 + l15 + c1o)*8];
      f16x8 a2 = *(const f16x8*)&c1s[((y + 2  )*17 + l15 + 2  )*8];
      f32x4 acc = {0.f,0.f,0.f,0.f};
      acc = __builtin_amdgcn_mfma_f32_16x16x32_f16(a0, bf0, acc, 0,0,0);
      acc = __builtin_amdgcn_mfma_f32_16x16x32_f16(a1, bf1, acc, 0,0,0);
      acc = __builtin_amdgcn_mfma_f32_16x16x32_f16(a2, bf2, acc, 0,0,0);
      const float m0 = fmaxf(acc[0], acc[1]);   // x = 4g,4g+1   -> px=2g
      const float m1 = fmaxf(acc[2], acc[3]);   // x = 4g+2,4g+3 -> px=2g+1
      if ((y & 1) == 0){ hA = m0; hB = m1; }
      else {
        const int py = y >> 1;
        const float vA = fmaxf(fmaxf(hA, m0) + bias2, 0.f);
        const float vB = fmaxf(fmaxf(hB, m1) + bias2, 0.f);
        c2ps[((py+1)*9 + (2*g+1))*24 + l15] = (f16)vA;        // px=2g
        if (g < 3)
          c2ps[((py+1)*9 + (2*g+2))*24 + l15] = (f16)vB;      // px=2g+1
      }
    }
  }
  wfence();

  // ---- conv3 (16->16, pad1) + bias + relu : A=image, B=weights ----
  // D[m=pix-in-tile=g*4+j][n=oc=l15]; store c3t[oc=l15][pix], b64.
  // Tile3 pix 49..63 are clamped duplicates of pix 48 (finite), zero pool wt.
  {
    f16x8 cf[5];
    #pragma unroll
    for (int kk=0; kk<5; ++kk)
      cf[kk] = *(const f16x8*)&wsw[OW3 + l15*160 + kk*32 + g*8];
    const float bias3 = b3g[l15];
    const int gh = g >> 1, icb = (g & 1)*8;
    #pragma unroll
    for (int tile=0; tile<4; ++tile){
      unsigned m = (unsigned)(tile*16 + l15); if (m > 48u) m = 48u;
      const int rcb = (int)(m/7u)*9 + (int)(m%7u);
      f32x4 acc = {0.f,0.f,0.f,0.f};
      #pragma unroll
      for (int kk=0; kk<5; ++kk){
        int p = 2*kk + gh; if (p > 8) p = 8;      // weight rows pos>=9 zero
        f16x8 a = *(const f16x8*)&c2ps[(rcb + (p/3)*9 + (p%3))*24 + icb];
        acc = __builtin_amdgcn_mfma_f32_16x16x32_f16(a, cf[kk], acc, 0,0,0);
      }
      union { f16 h[4]; unsigned long long u; } pk;
      #pragma unroll
      for (int j=0;j<4;++j) pk.h[j] = (f16)fmaxf(acc[j] + bias3, 0.f);
      *(unsigned long long*)&c3t[l15*72 + tile*16 + g*4] = pk.u;
    }
  }
  wfence();

  // ---- adaptive pool as 2 MFMAs: D[m=pq][n=oc] = 36*feat[oc][pq] ----
  // A=P36 (arg0, rows pq), B=c3t (arg1, cols oc). Lane reg j holds
  // 36*feat[oc=l15][pq=g*4+j] -> flatten t = l15*16 + g*4 + j.
  f32x4 pacc = {0.f,0.f,0.f,0.f};
  {
    const f16x8 pA0 = *(const f16x8*)&wsw[OPOOL + l15*64      + g*8];
    const f16x8 pA1 = *(const f16x8*)&wsw[OPOOL + l15*64 + 32 + g*8];
    const f16x8 pB0 = *(const f16x8*)&c3t[l15*72      + g*8];
    const f16x8 pB1 = *(const f16x8*)&c3t[l15*72 + 32 + g*8];
    pacc = __builtin_amdgcn_mfma_f32_16x16x32_f16(pA0, pB0, pacc, 0,0,0);
    pacc = __builtin_amdgcn_mfma_f32_16x16x32_f16(pA1, pB1, pacc, 0,0,0);
  }

  // ---- fc (256->4) + tanh*pi : shfl_xor butterfly (R3/R6-proven) ----
  {
    const float4 fw0 = *(const float4*)&fcwg[      l15*16 + g*4];
    const float4 fw1 = *(const float4*)&fcwg[256 + l15*16 + g*4];
    const float4 fw2 = *(const float4*)&fcwg[512 + l15*16 + g*4];
    const float4 fw3 = *(const float4*)&fcwg[768 + l15*16 + g*4];
    float s0 = pacc[0]*fw0.x + pacc[1]*fw0.y + pacc[2]*fw0.z + pacc[3]*fw0.w;
    float s1 = pacc[0]*fw1.x + pacc[1]*fw1.y + pacc[2]*fw1.z + pacc[3]*fw1.w;
    float s2 = pacc[0]*fw2.x + pacc[1]*fw2.y + pacc[2]*fw2.z + pacc[3]*fw2.w;
    float s3 = pacc[0]*fw3.x + pacc[1]*fw3.y + pacc[2]*fw3.z + pacc[3]*fw3.w;
    #pragma unroll
    for (int off=32; off; off>>=1){
      s0 += __shfl_xor(s0, off); s1 += __shfl_xor(s1, off);
      s2 += __shfl_xor(s2, off); s3 += __shfl_xor(s3, off);
    }
    if (lane < 4){
      const float s = (lane==0)?s0:(lane==1)?s1:(lane==2)?s2:s3;
      qin[(size_t)b*4 + lane] =
          tanhf(s*(1.f/36.f) + fcbg[lane]) * 3.14159265358979323846f;
    }
  }
}

// ---------------------------------------------------------------------------
// Kernel B: per-thread 4-qubit statevector sim + classifier head.
// wire w <-> bit mask (8 >> w)
// ---------------------------------------------------------------------------
template<int M>
__device__ __forceinline__ void g_ry(float* re, float* im, float c, float s){
  #pragma unroll
  for (int i=0;i<16;++i){
    if ((i & M)==0){
      const int j = i | M;
      const float r0=re[i], r1=re[j], q0=im[i], q1=im[j];
      re[i]=c*r0 - s*r1; re[j]=s*r0 + c*r1;
      im[i]=c*q0 - s*q1; im[j]=s*q0 + c*q1;
    }
  }
}
template<int M>
__device__ __forceinline__ void g_rz(float* re, float* im, float c, float s){
  #pragma unroll
  for (int i=0;i<16;++i){
    const float r=re[i], q=im[i];
    if ((i & M)==0){ re[i]=c*r + s*q; im[i]=c*q - s*r; }
    else           { re[i]=c*r - s*q; im[i]=c*q + s*r; }
  }
}
template<int CM,int TM>
__device__ __forceinline__ void g_cnot(float* re, float* im){
  #pragma unroll
  for (int i=0;i<16;++i){
    if ((i & CM) && !(i & TM)){
      const int j = i | TM;
      float t=re[i]; re[i]=re[j]; re[j]=t;
      t=im[i]; im[i]=im[j]; im[j]=t;
    }
  }
}

__global__ __launch_bounds__(256) void quantum_kernel(
    const float* __restrict__ qin, const float* __restrict__ qwg,
    const float* __restrict__ c1wg, const float* __restrict__ c1bg,
    const float* __restrict__ c2wg, const float* __restrict__ c2bg,
    float* __restrict__ out, int B)
{
  __shared__ float qc[32], qs[32], w1s[128], b1s[32], w2s[320], b2s[16];
  const int tid = threadIdx.x;
  if (tid < 32){ const float a = qwg[tid]*0.5f; qc[tid]=cosf(a); qs[tid]=sinf(a); }
  if (tid < 128) w1s[tid] = c1wg[tid];
  if (tid < 32)  b1s[tid] = c1bg[tid];
  for (int i=tid; i<320; i+=256) w2s[i] = c2wg[i];
  if (tid < 10)  b2s[tid] = c2bg[tid];
  __syncthreads();

  const int b = blockIdx.x*256 + tid;
  if (b >= B) return;

  const float4 ang = *(const float4*)(qin + (size_t)b*4);

  float re[16], im[16];
  #pragma unroll
  for (int i=0;i<16;++i){ re[i]=0.f; im[i]=0.f; }
  re[0] = 1.f;

  {
    float c,s;
    sincosf(ang.x*0.5f, &s, &c); g_ry<8>(re,im,c,s);
    sincosf(ang.y*0.5f, &s, &c); g_ry<4>(re,im,c,s);
    sincosf(ang.z*0.5f, &s, &c); g_ry<2>(re,im,c,s);
    sincosf(ang.w*0.5f, &s, &c); g_ry<1>(re,im,c,s);
  }

  #pragma unroll
  for (int l=0; l<4; ++l){
    const int o = l*8;
    g_ry<8>(re,im,qc[o+0],qs[o+0]);  g_rz<8>(re,im,qc[o+1],qs[o+1]);
    g_ry<4>(re,im,qc[o+2],qs[o+2]);  g_rz<4>(re,im,qc[o+3],qs[o+3]);
    g_ry<2>(re,im,qc[o+4],qs[o+4]);  g_rz<2>(re,im,qc[o+5],qs[o+5]);
    g_ry<1>(re,im,qc[o+6],qs[o+6]);  g_rz<1>(re,im,qc[o+7],qs[o+7]);
    g_cnot<8,4>(re,im); g_cnot<4,2>(re,im); g_cnot<2,1>(re,im); g_cnot<1,8>(re,im);
  }

  float p[16];
  #pragma unroll
  for (int i=0;i<16;++i) p[i] = re[i]*re[i] + im[i]*im[i];
  float z0=0.f, z1=0.f, z2=0.f, z3=0.f;
  #pragma unroll
  for (int i=0;i<16;++i){
    z0 += (i & 8) ? -p[i] : p[i];
    z1 += (i & 4) ? -p[i] : p[i];
    z2 += (i & 2) ? -p[i] : p[i];
    z3 += (i & 1) ? -p[i] : p[i];
  }

  float h[32];
  #pragma unroll
  for (int o=0;o<32;++o){
    const float v = b1s[o] + z0*w1s[o*4+0] + z1*w1s[o*4+1]
                           + z2*w1s[o*4+2] + z3*w1s[o*4+3];
    h[o] = fmaxf(v, 0.f);
  }
  #pragma unroll
  for (int o=0;o<10;++o){
    float v = b2s[o];
    #pragma unroll
    for (int k=0;k<32;++k) v += h[k]*w2s[o*32+k];
    out[(size_t)b*10 + o] = v;
  }
}

// ---------------------------------------------------------------------------
extern "C" void kernel_launch(void* const* d_in, const int* in_sizes, int n_in,
                              void* d_out, int out_size, void* d_ws, size_t ws_size,
                              hipStream_t stream)
{
  const float* x   = (const float*)d_in[0];
  const float* w1  = (const float*)d_in[1];
  const float* b1  = (const float*)d_in[2];
  const float* w2  = (const float*)d_in[3];
  const float* b2  = (const float*)d_in[4];
  const float* w3  = (const float*)d_in[5];
  const float* b3  = (const float*)d_in[6];
  const float* fcw = (const float*)d_in[7];
  const float* fcb = (const float*)d_in[8];
  const float* qw  = (const float*)d_in[9];
  const float* c1w = (const float*)d_in[10];
  const float* c1b = (const float*)d_in[11];
  const float* c2w = (const float*)d_in[12];
  const float* c2b = (const float*)d_in[13];
  float* outp = (float*)d_out;

  const int B = in_sizes[0] / 784;
  f16*   wsw = (f16*)d_ws;
  float* qin = (float*)((char*)d_ws + WS_QIN_OFF);

  precompute_weights<<<1, 256, 0, stream>>>(w1, w2, w3, wsw);

  classical_kernel<<<(B+3)/4, 256, 0, stream>>>(x, b1, b2, b3, fcw, fcb,
                                                wsw, qin, B);

  quantum_kernel<<<(B+255)/256, 256, 0, stream>>>(qin, qw, c1w, c1b,
                                                  c2w, c2b, outp, B);
}

// Round 14
// 79.056 us; speedup vs baseline: 1.0689x; 1.0681x over previous
//
#include <hip/hip_runtime.h>
#include <math.h>

typedef _Float16 f16;
typedef _Float16 f16x8 __attribute__((ext_vector_type(8)));
typedef float f32x4 __attribute__((ext_vector_type(4)));

// workspace: [0,16384) staged f16 weights; [16384, +B*16) qin
#define WS_QIN_OFF 16384
#define OW1   0      // [16][32] conv1 [oc][k] k=gk*8+ii: gk=ky, ii=1..3 -> kx=ii-1
#define OW2   512    // [16][96] conv2 [oc][pos12][ic8], pos>=9 zero
#define OW3   2048   // [16][160] conv3 [oc][k], k=pos*16+ic, pos>=9 zero
#define OPOOL 4608   // [16][64] 36x pool matrix (entries 9/6/4 exact f16)

// 4-byte-aligned 8-byte LDS load type -> compiler emits ds_read2_b32 (one
// instruction; no 8B-alignment assertion).
struct __attribute__((aligned(4))) u32pair { unsigned a, b; };

// wave-internal fence: drain this wave's LDS/VMEM so cross-lane RAW is safe
// without a block barrier (each wave owns its LDS region).
__device__ __forceinline__ void wfence(){
  __builtin_amdgcn_sched_barrier(0);
  asm volatile("s_waitcnt vmcnt(0) lgkmcnt(0)" ::: "memory");
  __builtin_amdgcn_sched_barrier(0);
}

// ---------------------------------------------------------------------------
__global__ void precompute_weights(const float* __restrict__ w1g,
                                   const float* __restrict__ w2g,
                                   const float* __restrict__ w3g,
                                   f16* __restrict__ wsw){
  const int tid = threadIdx.x;
  // conv1 weights (R4-proven): rows oc<8, chunk gk=ky, ii=0 is the kx=-1
  // garbage slot (zero weight), ii=1..3 -> kx=ii-1, ii>=4 zero.
  for (int i=tid; i<512; i+=256){
    int oc = i >> 5, k = i & 31, gk = k >> 3, ii = k & 7;
    float v = 0.f;
    if (oc < 8 && gk < 3 && ii >= 1 && ii <= 3) v = w1g[oc*9 + gk*3 + (ii-1)];
    wsw[OW1 + i] = (f16)v;
  }
  for (int i=tid; i<1536; i+=256){
    int oc = i/96, r = i%96, p = r>>3, ic = r&7;
    wsw[OW2 + i] = (f16)(p < 9 ? w2g[oc*72 + ic*9 + p] : 0.f);
  }
  for (int i=tid; i<2560; i+=256){
    int oc = i/160, k = i%160, pos = k>>4, ic = k&15;
    wsw[OW3 + i] = (f16)(pos < 9 ? w3g[oc*144 + ic*9 + pos] : 0.f);
  }
  // 36x adaptive-pool matrix: P36[pq][pix], exact {9,6,4} in f16
  for (int i=tid; i<1024; i+=256){
    int pq = i >> 6, pix = i & 63;
    float v = 0.f;
    if (pix < 49){
      int p = pq >> 2, q = pq & 3, ii = pix/7, jj = pix%7;
      int sp = (p*7) >> 2, ep = (7*(p+1)+3) >> 2;
      int sq = (q*7) >> 2, eq = (7*(q+1)+3) >> 2;
      if (ii >= sp && ii < ep && jj >= sq && jj < eq)
        v = 36.f / (float)((ep-sp)*(eq-sq));
    }
    wsw[OPOOL + i] = (f16)v;
  }
}

// ---------------------------------------------------------------------------
// One WAVE per sample, 4 waves/block, zero block barriers. All MFMA operands
// indexed with kappa(g,i)=g*8+i on both operands (HW k-perm cancels;
// validated R2-R13). D-mapping (pinned R2 conv2 + R4 conv3): D rows <- arg0's
// per-lane index, D cols <- arg1's; lane (l15,g) reg j holds D[g*4+j][l15].
// Layout = R7-proven: c1s [16 row][16 col][8 ic] (4096B), border rows 0,15 +
// cols 0,15 zeroed; col 16/17 overflow reads wrap into the same row's tail /
// next row col 0 -> feed only discarded D rows m=14,15 (finite garbage OK).
// ---------------------------------------------------------------------------
__global__ __launch_bounds__(256, 4) void classical_kernel(
    const float* __restrict__ xg,
    const float* __restrict__ b1g, const float* __restrict__ b2g,
    const float* __restrict__ b3g,
    const float* __restrict__ fcwg, const float* __restrict__ fcbg,
    const f16* __restrict__ wsw, float* __restrict__ qin, int B)
{
  // per-wave 7984B: region A [0,3888)    = xs [30][36] f16, later c2ps [81][24]
  //                 region B [3888,7984) = c1s [16][16][8] f16 = 4096B exactly
  __shared__ __align__(16) unsigned char pw[4][7984];

  const int tid = threadIdx.x, lane = tid & 63, wv = tid >> 6;
  const int l15 = lane & 15, g = lane >> 4;

  const int b = blockIdx.x*4 + wv;
  if (b >= B) return;

  f16* xs   = (f16*)&pw[wv][0];       // [30][36], col = x_img+4, row = y_img+1
  f16* c2ps = xs;                     // overlay: [81 pos][24 ch]
  f16* c1s  = (f16*)&pw[wv][3888];    // [16 row][16 col][8 ic]
  f16* c3t  = c1s;                    // overlay: [16 oc][72 pix] (144B rows)

  // ---- border-only zero: xs rows 0,29 + cols 2,3 (rows 1..28) = 64 u32 ----
  {
    unsigned* pz = (unsigned*)xs;     // rows of 18 dw
    int dw;
    if (lane < 18)      dw = lane;                      // row 0
    else if (lane < 36) dw = 29*18 + (lane - 18);       // row 29
    else                dw = (lane - 35)*18 + 1;        // rows 1..28, f16 cols 2,3
    pz[dw] = 0u;
  }
  // ---- border-only zero: c1s rows 0,15 + cols 0,15 (60 b128, R7-proven) ----
  {
    const f32x4 z4 = {0.f,0.f,0.f,0.f};
    f32x4* pz = (f32x4*)c1s;          // b128 idx = row*16 + col
    if (lane < 60){
      int dst;
      if (lane < 16)      dst = lane;                   // row 0
      else if (lane < 32) dst = 15*16 + (lane - 16);    // row 15
      else if (lane < 46) dst = (lane - 31)*16;         // col 0, rows 1..14
      else                dst = (lane - 45)*16 + 15;    // col 15, rows 1..14
      pz[dst] = z4;
    }
  }

  // ---- stage input: float4 global -> 4xf16 b64 LDS ----
  {
    const float4* xg4 = (const float4*)(xg + (size_t)b*784);
    #pragma unroll
    for (int r=0; r<4; ++r){
      const int idx = r*64 + lane;
      if (idx < 196){
        float4 v = xg4[idx];
        int y = idx/7, xq = idx - y*7;
        union { f16 h[4]; unsigned long long u; } pk;
        pk.h[0]=(f16)v.x; pk.h[1]=(f16)v.y; pk.h[2]=(f16)v.z; pk.h[3]=(f16)v.w;
        *(unsigned long long*)&xs[(y+1)*36 + xq*4 + 4] = pk.u;
      }
    }
  }
  wfence();

  // ---- conv1 (1->8, stride2, pad1) + relu via MFMA (R4-proven form) ----
  // A=weights (rows oc), B=image: chunk g = ky (g=3 all-zero weights), taps
  // i=0 -> kx=-1 (zero wt), i=1..3 -> kx=i-1, i>=4 zeroed in-reg.
  // D[oc=g*4+j][x=l15], write b64 (4 ic). Image read = ONE 8B ds_read2_b32.
  {
    const f16x8 aw = *(const f16x8*)&wsw[OW1 + l15*32 + g*8];
    const float4 bv = ((const float4*)b1g)[g & 1];   // oc g*4..g*4+3 (g<2)
    const unsigned* xsw = (const unsigned*)xs;       // u32 rows of 18
    for (int oy=0; oy<14; ++oy){
      const int bu = (2*oy + g)*18 + l15 + 1;        // f16 col 2*l15+2
      const u32pair rr = *(const u32pair*)&xsw[bu];
      union { unsigned u[4]; f16x8 v; } bf;
      bf.u[0] = rr.a; bf.u[1] = rr.b;
      bf.u[2] = 0u;   bf.u[3] = 0u;
      f32x4 acc = {0.f,0.f,0.f,0.f};
      acc = __builtin_amdgcn_mfma_f32_16x16x32_f16(aw, bf.v, acc, 0,0,0);
      if (g < 2 && l15 < 14){
        union { f16 h[4]; unsigned long long u; } pk;
        #pragma unroll
        for (int j=0;j<4;++j) pk.h[j] = (f16)fmaxf(acc[j] + bv[j], 0.f);
        *(unsigned long long*)&c1s[((oy+1)*16 + (l15+1))*8 + g*4] = pk.u;
      }
    }
  }
  wfence();

  // ---- conv2 (8->16, pad1) + maxpool2 + bias + relu via MFMA ----
  // A=image (m=x), B=weights (n=oc); pool folds in-register.
  {
    const f16x8 bf0 = *(const f16x8*)&wsw[OW2 + l15*96      + g*8];
    const f16x8 bf1 = *(const f16x8*)&wsw[OW2 + l15*96 + 32 + g*8];
    const f16x8 bf2 = *(const f16x8*)&wsw[OW2 + l15*96 + 64 + g*8];
    const float bias2 = b2g[l15];
    // border-only zero of c2ps (overlays dead xs): 32 border positions of the
    // 9x9 grid x ic0..15 (the only channels conv3 reads) = 64 b128, 1/lane.
    {
      const f32x4 z4 = {0.f,0.f,0.f,0.f};
      const int i = lane >> 1;
      int p;
      if (i < 9)       p = i;                 // row 0
      else if (i < 18) p = i + 63;            // row 8: 72..80
      else if (i < 25) p = 9*(i - 17);        // col 0: 9,18,..,63
      else             p = 9*(i - 24) + 8;    // col 8: 17,26,..,71
      *(f32x4*)&c2ps[p*24 + (lane & 1)*8] = z4;
    }
    const int p0 = g,     r0o = p0/3, c0o = p0%3;
    const int p1 = 4 + g, r1o = p1/3, c1o = p1%3;
    float hA = 0.f, hB = 0.f;
    for (int y=0; y<14; ++y){
      f16x8 a0 = *(const f16x8*)&c1s[((y + r0o)*16 + l15 + c0o)*8];
      f16x8 a1 = *(const f16x8*)&c1s[((y + r1o)*16 + l15 + c1o)*8];
      f16x8 a2 = *(const f16x8*)&c1s[((y + 2  )*16 + l15 + 2  )*8];
      f32x4 acc = {0.f,0.f,0.f,0.f};
      acc = __builtin_amdgcn_mfma_f32_16x16x32_f16(a0, bf0, acc, 0,0,0);
      acc = __builtin_amdgcn_mfma_f32_16x16x32_f16(a1, bf1, acc, 0,0,0);
      acc = __builtin_amdgcn_mfma_f32_16x16x32_f16(a2, bf2, acc, 0,0,0);
      const float m0 = fmaxf(acc[0], acc[1]);   // x = 4g,4g+1   -> px=2g
      const float m1 = fmaxf(acc[2], acc[3]);   // x = 4g+2,4g+3 -> px=2g+1
      if ((y & 1) == 0){ hA = m0; hB = m1; }
      else {
        const int py = y >> 1;
        const float vA = fmaxf(fmaxf(hA, m0) + bias2, 0.f);
        const float vB = fmaxf(fmaxf(hB, m1) + bias2, 0.f);
        c2ps[((py+1)*9 + (2*g+1))*24 + l15] = (f16)vA;        // px=2g
        if (g < 3)
          c2ps[((py+1)*9 + (2*g+2))*24 + l15] = (f16)vB;      // px=2g+1
      }
    }
  }
  wfence();

  // ---- conv3 (16->16, pad1) + bias + relu : A=image, B=weights ----
  // D[m=pix-in-tile=g*4+j][n=oc=l15]; store c3t[oc=l15][pix], b64.
  // Tile3 pix 49..63 are clamped duplicates of pix 48 (finite), zero pool wt.
  {
    f16x8 cf[5];
    #pragma unroll
    for (int kk=0; kk<5; ++kk)
      cf[kk] = *(const f16x8*)&wsw[OW3 + l15*160 + kk*32 + g*8];
    const float bias3 = b3g[l15];
    const int gh = g >> 1, icb = (g & 1)*8;
    #pragma unroll
    for (int tile=0; tile<4; ++tile){
      unsigned m = (unsigned)(tile*16 + l15); if (m > 48u) m = 48u;
      const int rcb = (int)(m/7u)*9 + (int)(m%7u);
      f32x4 acc = {0.f,0.f,0.f,0.f};
      #pragma unroll
      for (int kk=0; kk<5; ++kk){
        int p = 2*kk + gh; if (p > 8) p = 8;      // weight rows pos>=9 zero
        f16x8 a = *(const f16x8*)&c2ps[(rcb + (p/3)*9 + (p%3))*24 + icb];
        acc = __builtin_amdgcn_mfma_f32_16x16x32_f16(a, cf[kk], acc, 0,0,0);
      }
      union { f16 h[4]; unsigned long long u; } pk;
      #pragma unroll
      for (int j=0;j<4;++j) pk.h[j] = (f16)fmaxf(acc[j] + bias3, 0.f);
      *(unsigned long long*)&c3t[l15*72 + tile*16 + g*4] = pk.u;
    }
  }
  wfence();

  // ---- adaptive pool as 2 MFMAs: D[m=pq][n=oc] = 36*feat[oc][pq] ----
  // A=P36 (arg0, rows pq), B=c3t (arg1, cols oc). Lane reg j holds
  // 36*feat[oc=l15][pq=g*4+j] -> flatten t = l15*16 + g*4 + j.
  f32x4 pacc = {0.f,0.f,0.f,0.f};
  {
    const f16x8 pA0 = *(const f16x8*)&wsw[OPOOL + l15*64      + g*8];
    const f16x8 pA1 = *(const f16x8*)&wsw[OPOOL + l15*64 + 32 + g*8];
    const f16x8 pB0 = *(const f16x8*)&c3t[l15*72      + g*8];
    const f16x8 pB1 = *(const f16x8*)&c3t[l15*72 + 32 + g*8];
    pacc = __builtin_amdgcn_mfma_f32_16x16x32_f16(pA0, pB0, pacc, 0,0,0);
    pacc = __builtin_amdgcn_mfma_f32_16x16x32_f16(pA1, pB1, pacc, 0,0,0);
  }

  // ---- fc (256->4) + tanh*pi : shfl_xor butterfly (R3/R6-proven) ----
  {
    const float4 fw0 = *(const float4*)&fcwg[      l15*16 + g*4];
    const float4 fw1 = *(const float4*)&fcwg[256 + l15*16 + g*4];
    const float4 fw2 = *(const float4*)&fcwg[512 + l15*16 + g*4];
    const float4 fw3 = *(const float4*)&fcwg[768 + l15*16 + g*4];
    float s0 = pacc[0]*fw0.x + pacc[1]*fw0.y + pacc[2]*fw0.z + pacc[3]*fw0.w;
    float s1 = pacc[0]*fw1.x + pacc[1]*fw1.y + pacc[2]*fw1.z + pacc[3]*fw1.w;
    float s2 = pacc[0]*fw2.x + pacc[1]*fw2.y + pacc[2]*fw2.z + pacc[3]*fw2.w;
    float s3 = pacc[0]*fw3.x + pacc[1]*fw3.y + pacc[2]*fw3.z + pacc[3]*fw3.w;
    #pragma unroll
    for (int off=32; off; off>>=1){
      s0 += __shfl_xor(s0, off); s1 += __shfl_xor(s1, off);
      s2 += __shfl_xor(s2, off); s3 += __shfl_xor(s3, off);
    }
    if (lane < 4){
      const float s = (lane==0)?s0:(lane==1)?s1:(lane==2)?s2:s3;
      qin[(size_t)b*4 + lane] =
          tanhf(s*(1.f/36.f) + fcbg[lane]) * 3.14159265358979323846f;
    }
  }
}

// ---------------------------------------------------------------------------
// Kernel B: per-thread 4-qubit statevector sim + classifier head.
// wire w <-> bit mask (8 >> w)
// ---------------------------------------------------------------------------
template<int M>
__device__ __forceinline__ void g_ry(float* re, float* im, float c, float s){
  #pragma unroll
  for (int i=0;i<16;++i){
    if ((i & M)==0){
      const int j = i | M;
      const float r0=re[i], r1=re[j], q0=im[i], q1=im[j];
      re[i]=c*r0 - s*r1; re[j]=s*r0 + c*r1;
      im[i]=c*q0 - s*q1; im[j]=s*q0 + c*q1;
    }
  }
}
template<int M>
__device__ __forceinline__ void g_rz(float* re, float* im, float c, float s){
  #pragma unroll
  for (int i=0;i<16;++i){
    const float r=re[i], q=im[i];
    if ((i & M)==0){ re[i]=c*r + s*q; im[i]=c*q - s*r; }
    else           { re[i]=c*r - s*q; im[i]=c*q + s*r; }
  }
}
template<int CM,int TM>
__device__ __forceinline__ void g_cnot(float* re, float* im){
  #pragma unroll
  for (int i=0;i<16;++i){
    if ((i & CM) && !(i & TM)){
      const int j = i | TM;
      float t=re[i]; re[i]=re[j]; re[j]=t;
      t=im[i]; im[i]=im[j]; im[j]=t;
    }
  }
}

__global__ __launch_bounds__(256) void quantum_kernel(
    const float* __restrict__ qin, const float* __restrict__ qwg,
    const float* __restrict__ c1wg, const float* __restrict__ c1bg,
    const float* __restrict__ c2wg, const float* __restrict__ c2bg,
    float* __restrict__ out, int B)
{
  __shared__ float qc[32], qs[32], w1s[128], b1s[32], w2s[320], b2s[16];
  const int tid = threadIdx.x;
  if (tid < 32){ const float a = qwg[tid]*0.5f; qc[tid]=cosf(a); qs[tid]=sinf(a); }
  if (tid < 128) w1s[tid] = c1wg[tid];
  if (tid < 32)  b1s[tid] = c1bg[tid];
  for (int i=tid; i<320; i+=256) w2s[i] = c2wg[i];
  if (tid < 10)  b2s[tid] = c2bg[tid];
  __syncthreads();

  const int b = blockIdx.x*256 + tid;
  if (b >= B) return;

  const float4 ang = *(const float4*)(qin + (size_t)b*4);

  float re[16], im[16];
  #pragma unroll
  for (int i=0;i<16;++i){ re[i]=0.f; im[i]=0.f; }
  re[0] = 1.f;

  {
    float c,s;
    sincosf(ang.x*0.5f, &s, &c); g_ry<8>(re,im,c,s);
    sincosf(ang.y*0.5f, &s, &c); g_ry<4>(re,im,c,s);
    sincosf(ang.z*0.5f, &s, &c); g_ry<2>(re,im,c,s);
    sincosf(ang.w*0.5f, &s, &c); g_ry<1>(re,im,c,s);
  }

  #pragma unroll
  for (int l=0; l<4; ++l){
    const int o = l*8;
    g_ry<8>(re,im,qc[o+0],qs[o+0]);  g_rz<8>(re,im,qc[o+1],qs[o+1]);
    g_ry<4>(re,im,qc[o+2],qs[o+2]);  g_rz<4>(re,im,qc[o+3],qs[o+3]);
    g_ry<2>(re,im,qc[o+4],qs[o+4]);  g_rz<2>(re,im,qc[o+5],qs[o+5]);
    g_ry<1>(re,im,qc[o+6],qs[o+6]);  g_rz<1>(re,im,qc[o+7],qs[o+7]);
    g_cnot<8,4>(re,im); g_cnot<4,2>(re,im); g_cnot<2,1>(re,im); g_cnot<1,8>(re,im);
  }

  float p[16];
  #pragma unroll
  for (int i=0;i<16;++i) p[i] = re[i]*re[i] + im[i]*im[i];
  float z0=0.f, z1=0.f, z2=0.f, z3=0.f;
  #pragma unroll
  for (int i=0;i<16;++i){
    z0 += (i & 8) ? -p[i] : p[i];
    z1 += (i & 4) ? -p[i] : p[i];
    z2 += (i & 2) ? -p[i] : p[i];
    z3 += (i & 1) ? -p[i] : p[i];
  }

  float h[32];
  #pragma unroll
  for (int o=0;o<32;++o){
    const float v = b1s[o] + z0*w1s[o*4+0] + z1*w1s[o*4+1]
                           + z2*w1s[o*4+2] + z3*w1s[o*4+3];
    h[o] = fmaxf(v, 0.f);
  }
  #pragma unroll
  for (int o=0;o<10;++o){
    float v = b2s[o];
    #pragma unroll
    for (int k=0;k<32;++k) v += h[k]*w2s[o*32+k];
    out[(size_t)b*10 + o] = v;
  }
}

// ---------------------------------------------------------------------------
extern "C" void kernel_launch(void* const* d_in, const int* in_sizes, int n_in,
                              void* d_out, int out_size, void* d_ws, size_t ws_size,
                              hipStream_t stream)
{
  const float* x   = (const float*)d_in[0];
  const float* w1  = (const float*)d_in[1];
  const float* b1  = (const float*)d_in[2];
  const float* w2  = (const float*)d_in[3];
  const float* b2  = (const float*)d_in[4];
  const float* w3  = (const float*)d_in[5];
  const float* b3  = (const float*)d_in[6];
  const float* fcw = (const float*)d_in[7];
  const float* fcb = (const float*)d_in[8];
  const float* qw  = (const float*)d_in[9];
  const float* c1w = (const float*)d_in[10];
  const float* c1b = (const float*)d_in[11];
  const float* c2w = (const float*)d_in[12];
  const float* c2b = (const float*)d_in[13];
  float* outp = (float*)d_out;

  const int B = in_sizes[0] / 784;
  f16*   wsw = (f16*)d_ws;
  float* qin = (float*)((char*)d_ws + WS_QIN_OFF);

  precompute_weights<<<1, 256, 0, stream>>>(w1, w2, w3, wsw);

  classical_kernel<<<(B+3)/4, 256, 0, stream>>>(x, b1, b2, b3, fcw, fcb,
                                                wsw, qin, B);

  quantum_kernel<<<(B+255)/256, 256, 0, stream>>>(qin, qw, c1w, c1b,
                                                  c2w, c2b, outp, B);
}

// Round 15
// 77.074 us; speedup vs baseline: 1.0964x; 1.0257x over previous
//
#include <hip/hip_runtime.h>
#include <math.h>

typedef _Float16 f16;
typedef _Float16 f16x8 __attribute__((ext_vector_type(8)));
typedef float f32x4 __attribute__((ext_vector_type(4)));

// workspace: [0,16384) staged f16 weights; [16384, +B*16) qin
#define WS_QIN_OFF 16384
#define OW1   0      // [16][32] conv1 [oc][k] k=gk*8+ii: gk=ky, ii=1..3 -> kx=ii-1
#define OW2   512    // [16][96] conv2 [oc][p12][ic8], slot p=kk*4+g -> tap g*3+kk (g<3)
#define OW3   2048   // [16][160] conv3 [oc][k], k=pos*16+ic, pos>=9 zero
#define OPOOL 4608   // [16][64] 36x pool matrix (entries 9/6/4 exact f16)

// 4-byte-aligned 8-byte LDS load type -> compiler emits ds_read2_b32.
struct __attribute__((aligned(4))) u32pair { unsigned a, b; };

// wave-internal fence: drain this wave's LDS/VMEM so cross-lane RAW is safe
// without a block barrier (each wave owns its LDS region).
__device__ __forceinline__ void wfence(){
  __builtin_amdgcn_sched_barrier(0);
  asm volatile("s_waitcnt vmcnt(0) lgkmcnt(0)" ::: "memory");
  __builtin_amdgcn_sched_barrier(0);
}

// DPP row-shift-left by N lanes within each 16-lane row: dest lane i gets
// src lane i+N (anchor: AMD prefix-scan uses row_shr:N = lane i-N).
// bound_ctrl=true -> lanes with source >= row end read 0.
// Encodings: row_shl:1 = 0x101, row_shl:2 = 0x102.
template<int CTRL>
__device__ __forceinline__ f16x8 dpp_shl(f16x8 v){
  union { f16x8 h; int u[4]; } a, r;
  a.h = v;
  #pragma unroll
  for (int j=0;j<4;++j)
    r.u[j] = __builtin_amdgcn_update_dpp(0, a.u[j], CTRL, 0xf, 0xf, true);
  return r.h;
}

// ---------------------------------------------------------------------------
__global__ void precompute_weights(const float* __restrict__ w1g,
                                   const float* __restrict__ w2g,
                                   const float* __restrict__ w3g,
                                   f16* __restrict__ wsw){
  const int tid = threadIdx.x;
  // conv1 weights (R4-proven): rows oc<8, chunk gk=ky, ii=0 is the kx=-1
  // garbage slot (zero weight), ii=1..3 -> kx=ii-1, ii>=4 zero.
  for (int i=tid; i<512; i+=256){
    int oc = i >> 5, k = i & 31, gk = k >> 3, ii = k & 7;
    float v = 0.f;
    if (oc < 8 && gk < 3 && ii >= 1 && ii <= 3) v = w1g[oc*9 + gk*3 + (ii-1)];
    wsw[OW1 + i] = (f16)v;
  }
  // conv2: slot p = kk*4+g covers tap t = g*3+kk (row offset g, col offset kk)
  // for g<3; g=3 slots are zero (their A data is any finite value).
  for (int i=tid; i<1536; i+=256){
    int oc = i/96, r = i%96, p = r>>3, ic = r&7;
    int kk = p >> 2, g = p & 3;
    wsw[OW2 + i] = (f16)(g < 3 ? w2g[oc*72 + ic*9 + (g*3 + kk)] : 0.f);
  }
  for (int i=tid; i<2560; i+=256){
    int oc = i/160, k = i%160, pos = k>>4, ic = k&15;
    wsw[OW3 + i] = (f16)(pos < 9 ? w3g[oc*144 + ic*9 + pos] : 0.f);
  }
  // 36x adaptive-pool matrix: P36[pq][pix], exact {9,6,4} in f16
  for (int i=tid; i<1024; i+=256){
    int pq = i >> 6, pix = i & 63;
    float v = 0.f;
    if (pix < 49){
      int p = pq >> 2, q = pq & 3, ii = pix/7, jj = pix%7;
      int sp = (p*7) >> 2, ep = (7*(p+1)+3) >> 2;
      int sq = (q*7) >> 2, eq = (7*(q+1)+3) >> 2;
      if (ii >= sp && ii < ep && jj >= sq && jj < eq)
        v = 36.f / (float)((ep-sp)*(eq-sq));
    }
    wsw[OPOOL + i] = (f16)v;
  }
}

// ---------------------------------------------------------------------------
// One WAVE per sample, 4 waves/block, zero block barriers. All MFMA operands
// indexed with kappa(g,i)=g*8+i on both operands (HW k-perm cancels;
// validated R2-R14). D-mapping (pinned R2 conv2 + R4 conv3): D rows <- arg0's
// per-lane index, D cols <- arg1's; lane (l15,g) reg j holds D[g*4+j][l15].
// conv2 A-path (NEW): tap t = g*3+kk -> per y ONE b128 read (row y+g, col
// l15) + DPP row_shl:1/2 shifted copies feed kk=1,2. bound_ctrl zeros land
// only on lanes l15>=14 whose D rows m=14,15 are discarded.
// ---------------------------------------------------------------------------
__global__ __launch_bounds__(256, 4) void classical_kernel(
    const float* __restrict__ xg,
    const float* __restrict__ b1g, const float* __restrict__ b2g,
    const float* __restrict__ b3g,
    const float* __restrict__ fcwg, const float* __restrict__ fcbg,
    const f16* __restrict__ wsw, float* __restrict__ qin, int B)
{
  // per-wave 7984B: region A [0,3888)    = xs [30][36] f16, later c2ps [81][24]
  //                 region B [3888,7984) = c1s [16][16][8] f16 = 4096B exactly
  __shared__ __align__(16) unsigned char pw[4][7984];

  const int tid = threadIdx.x, lane = tid & 63, wv = tid >> 6;
  const int l15 = lane & 15, g = lane >> 4;

  const int b = blockIdx.x*4 + wv;
  if (b >= B) return;

  f16* xs   = (f16*)&pw[wv][0];       // [30][36], col = x_img+4, row = y_img+1
  f16* c2ps = xs;                     // overlay: [81 pos][24 ch]
  f16* c1s  = (f16*)&pw[wv][3888];    // [16 row][16 col][8 ic]
  f16* c3t  = c1s;                    // overlay: [16 oc][72 pix] (144B rows)

  // ---- border-only zero: xs rows 0,29 + cols 2,3 (rows 1..28) = 64 u32 ----
  {
    unsigned* pz = (unsigned*)xs;     // rows of 18 dw
    int dw;
    if (lane < 18)      dw = lane;                      // row 0
    else if (lane < 36) dw = 29*18 + (lane - 18);       // row 29
    else                dw = (lane - 35)*18 + 1;        // rows 1..28, f16 cols 2,3
    pz[dw] = 0u;
  }
  // ---- border-only zero: c1s rows 0,15 + cols 0,15 (60 b128, R7-proven) ----
  {
    const f32x4 z4 = {0.f,0.f,0.f,0.f};
    f32x4* pz = (f32x4*)c1s;          // b128 idx = row*16 + col
    if (lane < 60){
      int dst;
      if (lane < 16)      dst = lane;                   // row 0
      else if (lane < 32) dst = 15*16 + (lane - 16);    // row 15
      else if (lane < 46) dst = (lane - 31)*16;         // col 0, rows 1..14
      else                dst = (lane - 45)*16 + 15;    // col 15, rows 1..14
      pz[dst] = z4;
    }
  }

  // ---- stage input: float4 global -> 4xf16 b64 LDS ----
  {
    const float4* xg4 = (const float4*)(xg + (size_t)b*784);
    #pragma unroll
    for (int r=0; r<4; ++r){
      const int idx = r*64 + lane;
      if (idx < 196){
        float4 v = xg4[idx];
        int y = idx/7, xq = idx - y*7;
        union { f16 h[4]; unsigned long long u; } pk;
        pk.h[0]=(f16)v.x; pk.h[1]=(f16)v.y; pk.h[2]=(f16)v.z; pk.h[3]=(f16)v.w;
        *(unsigned long long*)&xs[(y+1)*36 + xq*4 + 4] = pk.u;
      }
    }
  }
  wfence();

  // ---- conv1 (1->8, stride2, pad1) + relu via MFMA (R4-proven form) ----
  // A=weights (rows oc), B=image: chunk g = ky (g=3 all-zero weights), taps
  // i=0 -> kx=-1 (zero wt), i=1..3 -> kx=i-1, i>=4 zeroed in-reg.
  // D[oc=g*4+j][x=l15], write b64 (4 ic). Image read = ONE 8B ds_read2_b32.
  {
    const f16x8 aw = *(const f16x8*)&wsw[OW1 + l15*32 + g*8];
    const float4 bv = ((const float4*)b1g)[g & 1];   // oc g*4..g*4+3 (g<2)
    const unsigned* xsw = (const unsigned*)xs;       // u32 rows of 18
    for (int oy=0; oy<14; ++oy){
      const int bu = (2*oy + g)*18 + l15 + 1;        // f16 col 2*l15+2
      const u32pair rr = *(const u32pair*)&xsw[bu];
      union { unsigned u[4]; f16x8 v; } bf;
      bf.u[0] = rr.a; bf.u[1] = rr.b;
      bf.u[2] = 0u;   bf.u[3] = 0u;
      f32x4 acc = {0.f,0.f,0.f,0.f};
      acc = __builtin_amdgcn_mfma_f32_16x16x32_f16(aw, bf.v, acc, 0,0,0);
      if (g < 2 && l15 < 14){
        union { f16 h[4]; unsigned long long u; } pk;
        #pragma unroll
        for (int j=0;j<4;++j) pk.h[j] = (f16)fmaxf(acc[j] + bv[j], 0.f);
        *(unsigned long long*)&c1s[((oy+1)*16 + (l15+1))*8 + g*4] = pk.u;
      }
    }
  }
  wfence();

  // ---- conv2 (8->16, pad1) + maxpool2 + bias + relu via MFMA ----
  // A=image (arg0, m=x=l15 per-lane), B=weights (arg1, n=oc=l15). Per y:
  // one b128 read (row y+g, col l15) + DPP row_shl:1/2 for kk=1,2.
  // g=3 chunk has all-zero weights -> reads row y+0 (finite, in-bounds).
  {
    const f16x8 bf0 = *(const f16x8*)&wsw[OW2 + l15*96      + g*8];
    const f16x8 bf1 = *(const f16x8*)&wsw[OW2 + l15*96 + 32 + g*8];
    const f16x8 bf2 = *(const f16x8*)&wsw[OW2 + l15*96 + 64 + g*8];
    const float bias2 = b2g[l15];
    // border-only zero of c2ps (overlays dead xs): 32 border positions of the
    // 9x9 grid x ic0..15 (the only channels conv3 reads) = 64 b128, 1/lane.
    {
      const f32x4 z4 = {0.f,0.f,0.f,0.f};
      const int i = lane >> 1;
      int p;
      if (i < 9)       p = i;                 // row 0
      else if (i < 18) p = i + 63;            // row 8: 72..80
      else if (i < 25) p = 9*(i - 17);        // col 0: 9,18,..,63
      else             p = 9*(i - 24) + 8;    // col 8: 17,26,..,71
      *(f32x4*)&c2ps[p*24 + (lane & 1)*8] = z4;
    }
    const int g3 = (g == 3) ? 0 : g;          // zero-weight chunk: any finite row
    float hA = 0.f, hB = 0.f;
    for (int y=0; y<14; ++y){
      const f16x8 a0 = *(const f16x8*)&c1s[((y + g3)*16 + l15)*8];
      const f16x8 a1 = dpp_shl<0x101>(a0);    // col l15+1
      const f16x8 a2 = dpp_shl<0x102>(a0);    // col l15+2
      f32x4 acc = {0.f,0.f,0.f,0.f};
      acc = __builtin_amdgcn_mfma_f32_16x16x32_f16(a0, bf0, acc, 0,0,0);
      acc = __builtin_amdgcn_mfma_f32_16x16x32_f16(a1, bf1, acc, 0,0,0);
      acc = __builtin_amdgcn_mfma_f32_16x16x32_f16(a2, bf2, acc, 0,0,0);
      const float m0 = fmaxf(acc[0], acc[1]);   // x = 4g,4g+1   -> px=2g
      const float m1 = fmaxf(acc[2], acc[3]);   // x = 4g+2,4g+3 -> px=2g+1
      if ((y & 1) == 0){ hA = m0; hB = m1; }
      else {
        const int py = y >> 1;
        const float vA = fmaxf(fmaxf(hA, m0) + bias2, 0.f);
        const float vB = fmaxf(fmaxf(hB, m1) + bias2, 0.f);
        c2ps[((py+1)*9 + (2*g+1))*24 + l15] = (f16)vA;        // px=2g
        if (g < 3)
          c2ps[((py+1)*9 + (2*g+2))*24 + l15] = (f16)vB;      // px=2g+1
      }
    }
  }
  wfence();

  // ---- conv3 (16->16, pad1) + bias + relu : A=image, B=weights ----
  // D[m=pix-in-tile=g*4+j][n=oc=l15]; store c3t[oc=l15][pix], b64.
  // Tile3 pix 49..63 are clamped duplicates of pix 48 (finite), zero pool wt.
  {
    f16x8 cf[5];
    #pragma unroll
    for (int kk=0; kk<5; ++kk)
      cf[kk] = *(const f16x8*)&wsw[OW3 + l15*160 + kk*32 + g*8];
    const float bias3 = b3g[l15];
    const int gh = g >> 1, icb = (g & 1)*8;
    #pragma unroll
    for (int tile=0; tile<4; ++tile){
      unsigned m = (unsigned)(tile*16 + l15); if (m > 48u) m = 48u;
      const int rcb = (int)(m/7u)*9 + (int)(m%7u);
      f32x4 acc = {0.f,0.f,0.f,0.f};
      #pragma unroll
      for (int kk=0; kk<5; ++kk){
        int p = 2*kk + gh; if (p > 8) p = 8;      // weight rows pos>=9 zero
        f16x8 a = *(const f16x8*)&c2ps[(rcb + (p/3)*9 + (p%3))*24 + icb];
        acc = __builtin_amdgcn_mfma_f32_16x16x32_f16(a, cf[kk], acc, 0,0,0);
      }
      union { f16 h[4]; unsigned long long u; } pk;
      #pragma unroll
      for (int j=0;j<4;++j) pk.h[j] = (f16)fmaxf(acc[j] + bias3, 0.f);
      *(unsigned long long*)&c3t[l15*72 + tile*16 + g*4] = pk.u;
    }
  }
  wfence();

  // ---- adaptive pool as 2 MFMAs: D[m=pq][n=oc] = 36*feat[oc][pq] ----
  // A=P36 (arg0, rows pq), B=c3t (arg1, cols oc). Lane reg j holds
  // 36*feat[oc=l15][pq=g*4+j] -> flatten t = l15*16 + g*4 + j.
  f32x4 pacc = {0.f,0.f,0.f,0.f};
  {
    const f16x8 pA0 = *(const f16x8*)&wsw[OPOOL + l15*64      + g*8];
    const f16x8 pA1 = *(const f16x8*)&wsw[OPOOL + l15*64 + 32 + g*8];
    const f16x8 pB0 = *(const f16x8*)&c3t[l15*72      + g*8];
    const f16x8 pB1 = *(const f16x8*)&c3t[l15*72 + 32 + g*8];
    pacc = __builtin_amdgcn_mfma_f32_16x16x32_f16(pA0, pB0, pacc, 0,0,0);
    pacc = __builtin_amdgcn_mfma_f32_16x16x32_f16(pA1, pB1, pacc, 0,0,0);
  }

  // ---- fc (256->4) + tanh*pi : shfl_xor butterfly (R3/R6-proven) ----
  {
    const float4 fw0 = *(const float4*)&fcwg[      l15*16 + g*4];
    const float4 fw1 = *(const float4*)&fcwg[256 + l15*16 + g*4];
    const float4 fw2 = *(const float4*)&fcwg[512 + l15*16 + g*4];
    const float4 fw3 = *(const float4*)&fcwg[768 + l15*16 + g*4];
    float s0 = pacc[0]*fw0.x + pacc[1]*fw0.y + pacc[2]*fw0.z + pacc[3]*fw0.w;
    float s1 = pacc[0]*fw1.x + pacc[1]*fw1.y + pacc[2]*fw1.z + pacc[3]*fw1.w;
    float s2 = pacc[0]*fw2.x + pacc[1]*fw2.y + pacc[2]*fw2.z + pacc[3]*fw2.w;
    float s3 = pacc[0]*fw3.x + pacc[1]*fw3.y + pacc[2]*fw3.z + pacc[3]*fw3.w;
    #pragma unroll
    for (int off=32; off; off>>=1){
      s0 += __shfl_xor(s0, off); s1 += __shfl_xor(s1, off);
      s2 += __shfl_xor(s2, off); s3 += __shfl_xor(s3, off);
    }
    if (lane < 4){
      const float s = (lane==0)?s0:(lane==1)?s1:(lane==2)?s2:s3;
      qin[(size_t)b*4 + lane] =
          tanhf(s*(1.f/36.f) + fcbg[lane]) * 3.14159265358979323846f;
    }
  }
}

// ---------------------------------------------------------------------------
// Kernel B: per-thread 4-qubit statevector sim + classifier head.
// wire w <-> bit mask (8 >> w)
// ---------------------------------------------------------------------------
template<int M>
__device__ __forceinline__ void g_ry(float* re, float* im, float c, float s){
  #pragma unroll
  for (int i=0;i<16;++i){
    if ((i & M)==0){
      const int j = i | M;
      const float r0=re[i], r1=re[j], q0=im[i], q1=im[j];
      re[i]=c*r0 - s*r1; re[j]=s*r0 + c*r1;
      im[i]=c*q0 - s*q1; im[j]=s*q0 + c*q1;
    }
  }
}
template<int M>
__device__ __forceinline__ void g_rz(float* re, float* im, float c, float s){
  #pragma unroll
  for (int i=0;i<16;++i){
    const float r=re[i], q=im[i];
    if ((i & M)==0){ re[i]=c*r + s*q; im[i]=c*q - s*r; }
    else           { re[i]=c*r - s*q; im[i]=c*q + s*r; }
  }
}
template<int CM,int TM>
__device__ __forceinline__ void g_cnot(float* re, float* im){
  #pragma unroll
  for (int i=0;i<16;++i){
    if ((i & CM) && !(i & TM)){
      const int j = i | TM;
      float t=re[i]; re[i]=re[j]; re[j]=t;
      t=im[i]; im[i]=im[j]; im[j]=t;
    }
  }
}

__global__ __launch_bounds__(256) void quantum_kernel(
    const float* __restrict__ qin, const float* __restrict__ qwg,
    const float* __restrict__ c1wg, const float* __restrict__ c1bg,
    const float* __restrict__ c2wg, const float* __restrict__ c2bg,
    float* __restrict__ out, int B)
{
  __shared__ float qc[32], qs[32], w1s[128], b1s[32], w2s[320], b2s[16];
  const int tid = threadIdx.x;
  if (tid < 32){ const float a = qwg[tid]*0.5f; qc[tid]=cosf(a); qs[tid]=sinf(a); }
  if (tid < 128) w1s[tid] = c1wg[tid];
  if (tid < 32)  b1s[tid] = c1bg[tid];
  for (int i=tid; i<320; i+=256) w2s[i] = c2wg[i];
  if (tid < 10)  b2s[tid] = c2bg[tid];
  __syncthreads();

  const int b = blockIdx.x*256 + tid;
  if (b >= B) return;

  const float4 ang = *(const float4*)(qin + (size_t)b*4);

  float re[16], im[16];
  #pragma unroll
  for (int i=0;i<16;++i){ re[i]=0.f; im[i]=0.f; }
  re[0] = 1.f;

  {
    float c,s;
    sincosf(ang.x*0.5f, &s, &c); g_ry<8>(re,im,c,s);
    sincosf(ang.y*0.5f, &s, &c); g_ry<4>(re,im,c,s);
    sincosf(ang.z*0.5f, &s, &c); g_ry<2>(re,im,c,s);
    sincosf(ang.w*0.5f, &s, &c); g_ry<1>(re,im,c,s);
  }

  #pragma unroll
  for (int l=0; l<4; ++l){
    const int o = l*8;
    g_ry<8>(re,im,qc[o+0],qs[o+0]);  g_rz<8>(re,im,qc[o+1],qs[o+1]);
    g_ry<4>(re,im,qc[o+2],qs[o+2]);  g_rz<4>(re,im,qc[o+3],qs[o+3]);
    g_ry<2>(re,im,qc[o+4],qs[o+4]);  g_rz<2>(re,im,qc[o+5],qs[o+5]);
    g_ry<1>(re,im,qc[o+6],qs[o+6]);  g_rz<1>(re,im,qc[o+7],qs[o+7]);
    g_cnot<8,4>(re,im); g_cnot<4,2>(re,im); g_cnot<2,1>(re,im); g_cnot<1,8>(re,im);
  }

  float p[16];
  #pragma unroll
  for (int i=0;i<16;++i) p[i] = re[i]*re[i] + im[i]*im[i];
  float z0=0.f, z1=0.f, z2=0.f, z3=0.f;
  #pragma unroll
  for (int i=0;i<16;++i){
    z0 += (i & 8) ? -p[i] : p[i];
    z1 += (i & 4) ? -p[i] : p[i];
    z2 += (i & 2) ? -p[i] : p[i];
    z3 += (i & 1) ? -p[i] : p[i];
  }

  float h[32];
  #pragma unroll
  for (int o=0;o<32;++o){
    const float v = b1s[o] + z0*w1s[o*4+0] + z1*w1s[o*4+1]
                           + z2*w1s[o*4+2] + z3*w1s[o*4+3];
    h[o] = fmaxf(v, 0.f);
  }
  #pragma unroll
  for (int o=0;o<10;++o){
    float v = b2s[o];
    #pragma unroll
    for (int k=0;k<32;++k) v += h[k]*w2s[o*32+k];
    out[(size_t)b*10 + o] = v;
  }
}

// ---------------------------------------------------------------------------
extern "C" void kernel_launch(void* const* d_in, const int* in_sizes, int n_in,
                              void* d_out, int out_size, void* d_ws, size_t ws_size,
                              hipStream_t stream)
{
  const float* x   = (const float*)d_in[0];
  const float* w1  = (const float*)d_in[1];
  const float* b1  = (const float*)d_in[2];
  const float* w2  = (const float*)d_in[3];
  const float* b2  = (const float*)d_in[4];
  const float* w3  = (const float*)d_in[5];
  const float* b3  = (const float*)d_in[6];
  const float* fcw = (const float*)d_in[7];
  const float* fcb = (const float*)d_in[8];
  const float* qw  = (const float*)d_in[9];
  const float* c1w = (const float*)d_in[10];
  const float* c1b = (const float*)d_in[11];
  const float* c2w = (const float*)d_in[12];
  const float* c2b = (const float*)d_in[13];
  float* outp = (float*)d_out;

  const int B = in_sizes[0] / 784;
  f16*   wsw = (f16*)d_ws;
  float* qin = (float*)((char*)d_ws + WS_QIN_OFF);

  precompute_weights<<<1, 256, 0, stream>>>(w1, w2, w3, wsw);

  classical_kernel<<<(B+3)/4, 256, 0, stream>>>(x, b1, b2, b3, fcw, fcb,
                                                wsw, qin, B);

  quantum_kernel<<<(B+255)/256, 256, 0, stream>>>(qin, qw, c1w, c1b,
                                                  c2w, c2b, outp, B);
}